// Round 9
// baseline (215.785 us; speedup 1.0000x reference)
//
#include <hip/hip_runtime.h>

// Green-Ampt infiltration scan. B=16384 rows x T=2048 steps.
//
// Evidence ledger:
//  R1: row-major 16B/lane stores -> 1.88x write amplification, 345us
//  R3: nontemporal -> 3.56x amplification, 1008us
//  R4: LDS transpose, full 128B lines -> 176us (~3 TB/s effective)
//  R5: 2-pass 8x concurrency -> null (ws-size fallback ambiguity)
//  R6: 512B runs -> null.  R7: DRAM-bank rotation -> slightly worse.
//  R8: producer/consumer wave split -> null. Store depth NOT the limit.
// Surviving theory: within every flush, all stores share address bits 8-12
// (same column phase for all rows/streams) -> ~192 lines into ~8 L2 sets
// -> set thrash caps writes at ~3 TB/s. Fill kernel (linear sweep, all set
// bits) gets 6.9 TB/s.
// R9: full-row contiguous flushes. Pass1 checkpoints F at 16 boundaries.
// Pass2: 1 wave = 4 rows x 16 segs; each lane recomputes its 128-step
// segment into LDS; flush = 3 linear 32KB contiguous sweeps (covers ALL
// set/channel bits, fill-like).

#define GA_MIN_INF 0.1f
#define GA_EPS 1e-6f

typedef float f4 __attribute__((ext_vector_type(4)));

constexpr int SEGS = 16;   // checkpoint segments
constexpr int RPB  = 4;    // rows per pass2 block
constexpr int PSEG = 132;  // LDS floats per (row,seg) chunk: 128 + 4 pad

__device__ __forceinline__ void ga_step(float& F, float Kv, float kpd,
                                        float pv, float& fi, float& ro) {
  float rF   = __builtin_amdgcn_rcpf(fmaxf(F, GA_EPS));
  float fcap = fmaxf(Kv + kpd * rF, GA_MIN_INF);
  float fact = fminf(pv, fcap);
  ro = fmaxf(pv - fact, 0.0f);
  F += fact;
  fi = fact;
}

// ---------------- Pass 1: state-only scan, checkpoint every T/SEGS steps ----
__global__ __launch_bounds__(64, 1) void ga_pass1(
    const float* __restrict__ precip, const float* __restrict__ K,
    const float* __restrict__ psi, const float* __restrict__ dtheta,
    float* __restrict__ cp, int B, int T) {
  const int b = blockIdx.x * 64 + threadIdx.x;
  if (b >= B) return;
  const float Kv  = K[b];
  const float kpd = Kv * (psi[b] * dtheta[b]);
  const f4* __restrict__ pr = reinterpret_cast<const f4*>(precip + (size_t)b * T);

  const int nbat = T / 32;                   // 64
  const int bats_per_seg = (T / SEGS) / 32;  // 4

  float F = 0.0f;
  f4 buf[8], nxt[8];
#pragma unroll
  for (int i = 0; i < 8; ++i) buf[i] = pr[i];

  for (int bat = 0; bat < nbat; ++bat) {
    if ((bat % bats_per_seg) == 0) cp[(size_t)(bat / bats_per_seg) * B + b] = F;
    if (bat + 1 < nbat) {
#pragma unroll
      for (int i = 0; i < 8; ++i) nxt[i] = pr[(bat + 1) * 8 + i];
    }
#pragma unroll
    for (int i = 0; i < 8; ++i) {
      const f4 p = buf[i];
#pragma unroll
      for (int j = 0; j < 4; ++j) {
        float fi_, ro_;
        ga_step(F, Kv, kpd, p[j], fi_, ro_);
      }
    }
#pragma unroll
    for (int i = 0; i < 8; ++i) buf[i] = nxt[i];
  }
}

// ---------------- Pass 2: segment recompute + full-row contiguous flush -----
__global__ __launch_bounds__(64, 1) void ga_pass2(
    const float* __restrict__ precip, const float* __restrict__ K,
    const float* __restrict__ psi, const float* __restrict__ dtheta,
    const float* __restrict__ cp, float* __restrict__ out, int B, int T) {
  __shared__ float sb0[RPB * SEGS * PSEG];   // infiltration
  __shared__ float sb1[RPB * SEGS * PSEG];   // runoff
  __shared__ float sb2[RPB * SEGS * PSEG];   // cumulative F

  const int lane = threadIdx.x;
  const int row  = lane & (RPB - 1);         // 0..3
  const int seg  = lane >> 2;                // 0..15
  const int rowbase = blockIdx.x * RPB;
  const int b = rowbase + row;

  const float Kv  = K[b];
  const float kpd = Kv * (psi[b] * dtheta[b]);

  const int seglen = T / SEGS;               // 128
  const int t0 = seg * seglen;
  float F = cp[(size_t)seg * B + b];

  const f4* __restrict__ pr = reinterpret_cast<const f4*>(precip + (size_t)b * T + t0);

  const int base_chunk = (row * SEGS + seg) * PSEG;

  // ---- compute this lane's 128-step segment into LDS ----
  f4 buf[8], nxt[8];
#pragma unroll
  for (int i = 0; i < 8; ++i) buf[i] = pr[i];

  for (int q = 0; q < 4; ++q) {              // 4 x 32 steps
    if (q < 3) {
#pragma unroll
      for (int i = 0; i < 8; ++i) nxt[i] = pr[(q + 1) * 8 + i];
    }
#pragma unroll
    for (int i = 0; i < 8; ++i) {
      const f4 p = buf[i];
      f4 a, r, c;
#pragma unroll
      for (int j = 0; j < 4; ++j) {
        float fi_, ro_;
        ga_step(F, Kv, kpd, p[j], fi_, ro_);
        a[j] = fi_; r[j] = ro_; c[j] = F;
      }
      const int tt = q * 32 + i * 4;
      *reinterpret_cast<f4*>(&sb0[base_chunk + tt]) = a;
      *reinterpret_cast<f4*>(&sb1[base_chunk + tt]) = r;
      *reinterpret_cast<f4*>(&sb2[base_chunk + tt]) = c;
    }
#pragma unroll
    for (int i = 0; i < 8; ++i) buf[i] = nxt[i];
  }

  __syncthreads();   // single wave: cheap; orders LDS writes before reads

  // ---- flush: per stream, one linear 32KB contiguous sweep ----
  const size_t BT = (size_t)B * (size_t)T;
  const size_t slab = (size_t)rowbase * T;
#pragma unroll
  for (int s = 0; s < 3; ++s) {
    const float* const src = (s == 0) ? sb0 : (s == 1) ? sb1 : sb2;
    float* const dst = out + (size_t)s * BT + slab;
#pragma unroll
    for (int f = 0; f < 32; ++f) {
      const int o  = f * 256 + lane * 4;     // float offset in 8192-float slab
      const int r  = o >> 11;                // /2048 : row within block
      const int c  = o & 2047;               // col within row
      const int sg = c >> 7;                 // /128 : segment
      const int tt = c & 127;                // t within segment
      f4 v = *reinterpret_cast<const f4*>(&src[(r * SEGS + sg) * PSEG + tt]);
      *reinterpret_cast<f4*>(dst + o) = v;
    }
  }
}

// ---------------- Fallback (R6-style single pass) if ws too small ----------
constexpr int FB_ROWS = 64, FB_TS = 128, FB_PITCH = 132;
__global__ __launch_bounds__(64, 1) void ga_mono(
    const float* __restrict__ precip, const float* __restrict__ K,
    const float* __restrict__ psi, const float* __restrict__ dtheta,
    float* __restrict__ out, int B, int T) {
  __shared__ float s0[FB_ROWS * FB_PITCH];
  __shared__ float s1[FB_ROWS * FB_PITCH];
  __shared__ float s2[FB_ROWS * FB_PITCH];
  const int lane = threadIdx.x;
  const int rowbase = blockIdx.x * FB_ROWS;
  const int b = rowbase + lane;
  const float Kv  = K[b];
  const float kpd = Kv * (psi[b] * dtheta[b]);
  const f4* __restrict__ pr = reinterpret_cast<const f4*>(precip + (size_t)b * T);
  const size_t BT = (size_t)B * (size_t)T;
  float* const o0 = out; float* const o1 = out + BT; float* const o2 = out + 2 * BT;
  const int fr = lane >> 5, fc = (lane & 31) * 4;
  const int nstage = T / FB_TS, nsb = T / 32;
  float F = 0.0f;
  f4 buf[8], nxt[8];
#pragma unroll
  for (int i = 0; i < 8; ++i) buf[i] = pr[i];
  int sbc = 0;
  for (int st = 0; st < nstage; ++st) {
#pragma unroll
    for (int q = 0; q < 4; ++q) {
      if (sbc + 1 < nsb) {
#pragma unroll
        for (int i = 0; i < 8; ++i) nxt[i] = pr[(sbc + 1) * 8 + i];
      }
#pragma unroll
      for (int i = 0; i < 8; ++i) {
        const f4 p = buf[i]; f4 a, r, c;
#pragma unroll
        for (int j = 0; j < 4; ++j) {
          float fi_, ro_; ga_step(F, Kv, kpd, p[j], fi_, ro_);
          a[j] = fi_; r[j] = ro_; c[j] = F;
        }
        const int t0 = q * 32 + i * 4;
        *reinterpret_cast<f4*>(&s0[lane * FB_PITCH + t0]) = a;
        *reinterpret_cast<f4*>(&s1[lane * FB_PITCH + t0]) = r;
        *reinterpret_cast<f4*>(&s2[lane * FB_PITCH + t0]) = c;
      }
#pragma unroll
      for (int i = 0; i < 8; ++i) buf[i] = nxt[i];
      ++sbc;
    }
    const int tb = st * FB_TS;
#pragma unroll
    for (int g = 0; g < 32; ++g) {
      const int r = 2 * g + fr;
      const size_t go = (size_t)(rowbase + r) * T + tb + fc;
      const int lo = r * FB_PITCH + fc;
      *reinterpret_cast<f4*>(o0 + go) = *reinterpret_cast<const f4*>(&s0[lo]);
      *reinterpret_cast<f4*>(o1 + go) = *reinterpret_cast<const f4*>(&s1[lo]);
      *reinterpret_cast<f4*>(o2 + go) = *reinterpret_cast<const f4*>(&s2[lo]);
    }
  }
}

extern "C" void kernel_launch(void* const* d_in, const int* in_sizes, int n_in,
                              void* d_out, int out_size, void* d_ws, size_t ws_size,
                              hipStream_t stream) {
  const float* precip = (const float*)d_in[0];
  const float* K      = (const float*)d_in[1];
  const float* psi    = (const float*)d_in[2];
  const float* dtheta = (const float*)d_in[3];
  float* out = (float*)d_out;

  const int B = in_sizes[1];            // K has B elements
  const int T = in_sizes[0] / B;        // precip is B*T

  const size_t cp_bytes = (size_t)SEGS * (size_t)B * sizeof(float);
  const bool ok = (B % RPB) == 0 && (T % SEGS) == 0 &&
                  ((T / SEGS) % 32) == 0 && (T % 2048) == 0;

  if (ws_size >= cp_bytes && ok) {
    float* cp = (float*)d_ws;
    ga_pass1<<<B / 64, 64, 0, stream>>>(precip, K, psi, dtheta, cp, B, T);
    ga_pass2<<<B / RPB, 64, 0, stream>>>(precip, K, psi, dtheta, cp, out, B, T);
  } else {
    ga_mono<<<B / FB_ROWS, 64, 0, stream>>>(precip, K, psi, dtheta, out, B, T);
  }
}

// Round 10
// 132.179 us; speedup vs baseline: 1.6325x; 1.6325x over previous
//
#include <hip/hip_runtime.h>

// Green-Ampt infiltration scan. B=16384 rows x T=2048 steps. Single pass.
//
// Evidence ledger:
//  R1: row-major 16B/lane stores -> 1.88x write amplification, 345us
//  R3: nontemporal SCATTERED 16B stores -> 3.56x amplification, 1008us
//  R4: LDS transpose, full 128B lines -> 176us (~2.7 TB/s writes)
//  R5: 2-pass 8x concurrency -> ~null.  R6: 512B runs -> null (177us).
//  R7: DRAM-bank rotation -> worse.    R8: producer/consumer waves -> null.
//  R9: fully contiguous 32KB slab flushes -> worse (175us pass2).
// All cache-path variants pin at ~2.7-3.3 TB/s writes; rocclr fillBuffer
// does 6.9 TB/s on the same buffer. Last untested axis: store CACHE PATH.
// R10 = R6 exactly, but flush stores are nontemporal. Unlike R3, each store
// instruction here is wave-contiguous (64 lanes x 16B = 1KB = 8 full 128B
// lines) -> no partial-line RMW; nt streams past L2/L3, leaving L3 for
// precip reads.

#define GA_MIN_INF 0.1f
#define GA_EPS 1e-6f

typedef float f4 __attribute__((ext_vector_type(4)));

constexpr int ROWS   = 64;    // rows per block (= lanes)
constexpr int TSTAGE = 128;   // timesteps staged per flush (512B/row/stream)
constexpr int PITCH  = 132;   // LDS row pitch in floats (16B-aligned, odd f4)

__global__ __launch_bounds__(64, 1) void ga_kernel(
    const float* __restrict__ precip, const float* __restrict__ K,
    const float* __restrict__ psi, const float* __restrict__ dtheta,
    float* __restrict__ out, int B, int T) {
  __shared__ float s0[ROWS * PITCH];   // infiltration
  __shared__ float s1[ROWS * PITCH];   // runoff
  __shared__ float s2[ROWS * PITCH];   // cumulative F

  const int lane = threadIdx.x;
  const int rowbase = blockIdx.x * ROWS;
  const int b = rowbase + lane;

  const float Kv  = K[b];
  const float kpd = Kv * (psi[b] * dtheta[b]);

  const f4* __restrict__ pr = reinterpret_cast<const f4*>(precip + (size_t)b * T);

  const size_t BT = (size_t)B * (size_t)T;
  float* const o0 = out;
  float* const o1 = out + BT;
  float* const o2 = out + 2 * BT;

  // Flush mapping: instr g covers rows {2g, 2g+1}; each row's 512B is
  // written by 32 lanes contiguously -> 1KB contiguous per instruction.
  const int fr = lane >> 5;          // 0..1 : which row of the pair
  const int fc = (lane & 31) * 4;    // float col 0,4,...,124

  const int nstage = T / TSTAGE;     // 16
  const int nsb = T / 32;            // 32-step sub-batches per row (64)
  float F = 0.0f;

  f4 buf[8], nxt[8];
#pragma unroll
  for (int i = 0; i < 8; ++i) buf[i] = pr[i];

  int sb = 0;
  for (int st = 0; st < nstage; ++st) {
    // ---- compute TSTAGE steps = 4 sub-batches of 32, results into LDS ----
#pragma unroll
    for (int q = 0; q < 4; ++q) {
      if (sb + 1 < nsb) {
#pragma unroll
        for (int i = 0; i < 8; ++i) nxt[i] = pr[(sb + 1) * 8 + i];
      }
#pragma unroll
      for (int i = 0; i < 8; ++i) {
        const f4 p = buf[i];
        f4 a, r, c;
#pragma unroll
        for (int j = 0; j < 4; ++j) {
          float rF   = __builtin_amdgcn_rcpf(fmaxf(F, GA_EPS));
          float fcap = fmaxf(Kv + kpd * rF, GA_MIN_INF);
          float fact = fminf(p[j], fcap);
          r[j] = fmaxf(p[j] - fact, 0.0f);
          F += fact;
          a[j] = fact;
          c[j] = F;
        }
        const int t0 = q * 32 + i * 4;
        *reinterpret_cast<f4*>(&s0[lane * PITCH + t0]) = a;
        *reinterpret_cast<f4*>(&s1[lane * PITCH + t0]) = r;
        *reinterpret_cast<f4*>(&s2[lane * PITCH + t0]) = c;
      }
#pragma unroll
      for (int i = 0; i < 8; ++i) buf[i] = nxt[i];
      ++sb;
    }

    // ---- flush: 32 instrs/stream, 1KB contiguous each, NONTEMPORAL ----
    const int tb = st * TSTAGE;
#pragma unroll
    for (int g = 0; g < 32; ++g) {
      const int r = 2 * g + fr;
      const size_t go = (size_t)(rowbase + r) * T + tb + fc;
      const int lo = r * PITCH + fc;
      f4 v0 = *reinterpret_cast<const f4*>(&s0[lo]);
      f4 v1 = *reinterpret_cast<const f4*>(&s1[lo]);
      f4 v2 = *reinterpret_cast<const f4*>(&s2[lo]);
      __builtin_nontemporal_store(v0, reinterpret_cast<f4*>(o0 + go));
      __builtin_nontemporal_store(v1, reinterpret_cast<f4*>(o1 + go));
      __builtin_nontemporal_store(v2, reinterpret_cast<f4*>(o2 + go));
    }
  }
}

// Fallback for shapes not divisible by the tiling (not hit for 16384x2048).
__global__ void ga_fallback(
    const float* __restrict__ precip, const float* __restrict__ K,
    const float* __restrict__ psi, const float* __restrict__ dtheta,
    float* __restrict__ out, int B, int T) {
  int b = blockIdx.x * blockDim.x + threadIdx.x;
  if (b >= B) return;
  const float Kv  = K[b];
  const float kpd = Kv * (psi[b] * dtheta[b]);
  const size_t BT = (size_t)B * (size_t)T;
  float F = 0.0f;
  for (int t = 0; t < T; ++t) {
    float pv   = precip[(size_t)b * T + t];
    float rF   = __builtin_amdgcn_rcpf(fmaxf(F, GA_EPS));
    float fcap = fmaxf(Kv + kpd * rF, GA_MIN_INF);
    float fact = fminf(pv, fcap);
    float ro   = fmaxf(pv - fact, 0.0f);
    F += fact;
    out[(size_t)b * T + t] = fact;
    out[BT + (size_t)b * T + t] = ro;
    out[2 * BT + (size_t)b * T + t] = F;
  }
}

extern "C" void kernel_launch(void* const* d_in, const int* in_sizes, int n_in,
                              void* d_out, int out_size, void* d_ws, size_t ws_size,
                              hipStream_t stream) {
  const float* precip = (const float*)d_in[0];
  const float* K      = (const float*)d_in[1];
  const float* psi    = (const float*)d_in[2];
  const float* dtheta = (const float*)d_in[3];
  float* out = (float*)d_out;

  const int B = in_sizes[1];            // K has B elements
  const int T = in_sizes[0] / B;        // precip is B*T

  if ((B % ROWS) == 0 && (T % TSTAGE) == 0) {
    ga_kernel<<<B / ROWS, 64, 0, stream>>>(precip, K, psi, dtheta, out, B, T);
  } else {
    ga_fallback<<<(B + 63) / 64, 64, 0, stream>>>(precip, K, psi, dtheta, out, B, T);
  }
}

// Round 11
// 119.922 us; speedup vs baseline: 1.7994x; 1.1022x over previous
//
#include <hip/hip_runtime.h>

// Green-Ampt infiltration scan. B=16384 rows x T=2048 steps. Single pass,
// producer/consumer wave split + NONTEMPORAL flush stores.
//
// Evidence ledger:
//  R1:  16B/lane cached stores -> 1.88x write amplification, 345us
//  R3:  nt SCATTERED 16B stores -> 3.56x amplification (partial-line RMW)
//  R4:  LDS transpose, full 128B lines -> 176us (~2.7 TB/s writes)
//  R5-R9: concurrency/run-length/bank-rotation/L2-set variants -> all null
//         in the CACHED-store regime (cache path was the wall).
//  R10: wave-contiguous nt stores -> 132us (~4.1 TB/s). Cache path confirmed.
// R11: re-test store concurrency IN THE NT REGIME: wave0 computes into
// double-buffered LDS; waves1-3 each drain one stream nt. Raw s_barrier
// (no vmcnt drain) so stores pipeline across stages; 3x store-issue waves.

#define GA_MIN_INF 0.1f
#define GA_EPS 1e-6f

typedef float f4 __attribute__((ext_vector_type(4)));

constexpr int ROWS  = 64;   // rows per block (= lanes of wave 0)
constexpr int TS    = 64;   // timesteps per stage (256B per row per stream)
constexpr int PITCH = 68;   // LDS row pitch in floats (16B-aligned)

__global__ __launch_bounds__(256, 1) void ga_pc(
    const float* __restrict__ precip, const float* __restrict__ K,
    const float* __restrict__ psi, const float* __restrict__ dtheta,
    float* __restrict__ out, int B, int T) {
  __shared__ float sb[2][3][ROWS * PITCH];   // [parity][stream][row*PITCH+t]

  const int tid  = threadIdx.x;
  const int wid  = tid >> 6;
  const int lane = tid & 63;
  const int rowbase = blockIdx.x * ROWS;

  const size_t BT = (size_t)B * (size_t)T;
  const int nstage = T / TS;                 // 32
  const int nsb    = T / 32;                 // 32-step sub-batches (64)

  if (wid == 0) {
    // ---------------- producer: serial recurrence into LDS stages ----------
    const int b = rowbase + lane;
    const float Kv  = K[b];
    const float kpd = Kv * (psi[b] * dtheta[b]);
    const f4* __restrict__ pr = reinterpret_cast<const f4*>(precip + (size_t)b * T);

    float F = 0.0f;
    f4 buf[8], nxt[8];
#pragma unroll
    for (int i = 0; i < 8; ++i) buf[i] = pr[i];

    int sbc = 0;
    for (int st = 0; st < nstage; ++st) {
      const int pb = st & 1;
      float* const L0 = &sb[pb][0][lane * PITCH];
      float* const L1 = &sb[pb][1][lane * PITCH];
      float* const L2 = &sb[pb][2][lane * PITCH];
#pragma unroll
      for (int q = 0; q < 2; ++q) {          // 2 x 32 steps = TS
        if (sbc + 1 < nsb) {
#pragma unroll
          for (int i = 0; i < 8; ++i) nxt[i] = pr[(sbc + 1) * 8 + i];
        }
#pragma unroll
        for (int i = 0; i < 8; ++i) {
          const f4 p = buf[i];
          f4 a, r, c;
#pragma unroll
          for (int j = 0; j < 4; ++j) {
            float rF   = __builtin_amdgcn_rcpf(fmaxf(F, GA_EPS));
            float fcap = fmaxf(Kv + kpd * rF, GA_MIN_INF);
            float fact = fminf(p[j], fcap);
            r[j] = fmaxf(p[j] - fact, 0.0f);
            F += fact;
            a[j] = fact;
            c[j] = F;
          }
          const int t0 = q * 32 + i * 4;
          *reinterpret_cast<f4*>(L0 + t0) = a;
          *reinterpret_cast<f4*>(L1 + t0) = r;
          *reinterpret_cast<f4*>(L2 + t0) = c;
        }
#pragma unroll
        for (int i = 0; i < 8; ++i) buf[i] = nxt[i];
        ++sbc;
      }
      // LDS writes visible before consumers cross the barrier; no vmcnt drain.
      asm volatile("s_waitcnt lgkmcnt(0)" ::: "memory");
      __builtin_amdgcn_s_barrier();
    }
  } else {
    // ---------------- consumers: one wave per output stream, nt stores -----
    const int s = wid - 1;
    float* const dst = out + (size_t)s * BT;
    const int fr = lane >> 4;                // 0..3 : row within quad
    const int fc = (lane & 15) * 4;          // float col 0..60

    for (int st = 0; st < nstage; ++st) {
      if (st > 0) {
        const int tb = (st - 1) * TS;
        const float* const src = &sb[(st - 1) & 1][s][0];
#pragma unroll
        for (int g = 0; g < 16; ++g) {
          const int r = g * 4 + fr;
          f4 v = *reinterpret_cast<const f4*>(&src[r * PITCH + fc]);
          __builtin_nontemporal_store(
              v, reinterpret_cast<f4*>(dst + (size_t)(rowbase + r) * T + tb + fc));
        }
      }
      // ds_reads of this stage already forced complete by store data deps;
      // cheap drain + compile-time fence keeps them on this side of the barrier.
      asm volatile("s_waitcnt lgkmcnt(0)" ::: "memory");
      __builtin_amdgcn_s_barrier();
    }
    // drain final stage (producer is done; no barrier needed)
    {
      const int tb = (nstage - 1) * TS;
      const float* const src = &sb[(nstage - 1) & 1][s][0];
#pragma unroll
      for (int g = 0; g < 16; ++g) {
        const int r = g * 4 + fr;
        f4 v = *reinterpret_cast<const f4*>(&src[r * PITCH + fc]);
        __builtin_nontemporal_store(
            v, reinterpret_cast<f4*>(dst + (size_t)(rowbase + r) * T + tb + fc));
      }
    }
  }
}

// Fallback for shapes not divisible by the tiling (not hit for 16384x2048).
__global__ void ga_fallback(
    const float* __restrict__ precip, const float* __restrict__ K,
    const float* __restrict__ psi, const float* __restrict__ dtheta,
    float* __restrict__ out, int B, int T) {
  int b = blockIdx.x * blockDim.x + threadIdx.x;
  if (b >= B) return;
  const float Kv  = K[b];
  const float kpd = Kv * (psi[b] * dtheta[b]);
  const size_t BT = (size_t)B * (size_t)T;
  float F = 0.0f;
  for (int t = 0; t < T; ++t) {
    float pv   = precip[(size_t)b * T + t];
    float rF   = __builtin_amdgcn_rcpf(fmaxf(F, GA_EPS));
    float fcap = fmaxf(Kv + kpd * rF, GA_MIN_INF);
    float fact = fminf(pv, fcap);
    float ro   = fmaxf(pv - fact, 0.0f);
    F += fact;
    out[(size_t)b * T + t] = fact;
    out[BT + (size_t)b * T + t] = ro;
    out[2 * BT + (size_t)b * T + t] = F;
  }
}

extern "C" void kernel_launch(void* const* d_in, const int* in_sizes, int n_in,
                              void* d_out, int out_size, void* d_ws, size_t ws_size,
                              hipStream_t stream) {
  const float* precip = (const float*)d_in[0];
  const float* K      = (const float*)d_in[1];
  const float* psi    = (const float*)d_in[2];
  const float* dtheta = (const float*)d_in[3];
  float* out = (float*)d_out;

  const int B = in_sizes[1];            // K has B elements
  const int T = in_sizes[0] / B;        // precip is B*T

  if ((B % ROWS) == 0 && (T % TS) == 0 && ((T / 32) % 2) == 0) {
    ga_pc<<<B / ROWS, 256, 0, stream>>>(precip, K, psi, dtheta, out, B, T);
  } else {
    ga_fallback<<<(B + 63) / 64, 64, 0, stream>>>(precip, K, psi, dtheta, out, B, T);
  }
}

// Round 12
// 105.996 us; speedup vs baseline: 2.0358x; 1.1314x over previous
//
#include <hip/hip_runtime.h>

// Green-Ampt infiltration scan. B=16384 rows x T=2048 steps. Single pass,
// producer/consumer wave split + NONTEMPORAL flush stores.
//
// Evidence ledger:
//  R1:  16B/lane cached stores -> 1.88x write amplification, 345us
//  R3:  nt SCATTERED 16B stores -> 3.56x amplification (partial-line RMW)
//  R4:  LDS transpose, full 128B lines -> 176us (~2.7 TB/s writes)
//  R5-R9: concurrency/run-length/bank/L2-set variants under CACHED stores
//         -> all null (cached-write path was the wall at ~3 TB/s)
//  R10: wave-contiguous nt stores -> 132us (~4.1 TB/s). Cache path confirmed.
//  R11: +3 dedicated store waves, raw barriers -> 120us (~4.5 TB/s).
// Stage arithmetic: producer 0.7us vs stage 3.75us -> consumers still the
// critical path at ~13 GB/s/CU (fill: ~27). R12: 6 consumer waves (2 per
// stream, row-halves) = 2x store-issue width. Else identical to R11.

#define GA_MIN_INF 0.1f
#define GA_EPS 1e-6f

typedef float f4 __attribute__((ext_vector_type(4)));

constexpr int ROWS  = 64;   // rows per block (= lanes of wave 0)
constexpr int TS    = 64;   // timesteps per stage (256B per row per stream)
constexpr int PITCH = 68;   // LDS row pitch in floats (16B-aligned)

__global__ __launch_bounds__(448, 1) void ga_pc(
    const float* __restrict__ precip, const float* __restrict__ K,
    const float* __restrict__ psi, const float* __restrict__ dtheta,
    float* __restrict__ out, int B, int T) {
  __shared__ float sb[2][3][ROWS * PITCH];   // [parity][stream][row*PITCH+t]

  const int tid  = threadIdx.x;
  const int wid  = tid >> 6;
  const int lane = tid & 63;
  const int rowbase = blockIdx.x * ROWS;

  const size_t BT = (size_t)B * (size_t)T;
  const int nstage = T / TS;                 // 32
  const int nsb    = T / 32;                 // 32-step sub-batches (64)

  if (wid == 0) {
    // ---------------- producer: serial recurrence into LDS stages ----------
    const int b = rowbase + lane;
    const float Kv  = K[b];
    const float kpd = Kv * (psi[b] * dtheta[b]);
    const f4* __restrict__ pr = reinterpret_cast<const f4*>(precip + (size_t)b * T);

    float F = 0.0f;
    f4 buf[8], nxt[8];
#pragma unroll
    for (int i = 0; i < 8; ++i) buf[i] = pr[i];

    int sbc = 0;
    for (int st = 0; st < nstage; ++st) {
      const int pb = st & 1;
      float* const L0 = &sb[pb][0][lane * PITCH];
      float* const L1 = &sb[pb][1][lane * PITCH];
      float* const L2 = &sb[pb][2][lane * PITCH];
#pragma unroll
      for (int q = 0; q < 2; ++q) {          // 2 x 32 steps = TS
        if (sbc + 1 < nsb) {
#pragma unroll
          for (int i = 0; i < 8; ++i) nxt[i] = pr[(sbc + 1) * 8 + i];
        }
#pragma unroll
        for (int i = 0; i < 8; ++i) {
          const f4 p = buf[i];
          f4 a, r, c;
#pragma unroll
          for (int j = 0; j < 4; ++j) {
            float rF   = __builtin_amdgcn_rcpf(fmaxf(F, GA_EPS));
            float fcap = fmaxf(Kv + kpd * rF, GA_MIN_INF);
            float fact = fminf(p[j], fcap);
            r[j] = fmaxf(p[j] - fact, 0.0f);
            F += fact;
            a[j] = fact;
            c[j] = F;
          }
          const int t0 = q * 32 + i * 4;
          *reinterpret_cast<f4*>(L0 + t0) = a;
          *reinterpret_cast<f4*>(L1 + t0) = r;
          *reinterpret_cast<f4*>(L2 + t0) = c;
        }
#pragma unroll
        for (int i = 0; i < 8; ++i) buf[i] = nxt[i];
        ++sbc;
      }
      // LDS writes visible before consumers cross the barrier; no vmcnt drain.
      asm volatile("s_waitcnt lgkmcnt(0)" ::: "memory");
      __builtin_amdgcn_s_barrier();
    }
  } else {
    // ------------- consumers: 2 waves per stream (row halves), nt stores ---
    const int s = (wid - 1) % 3;             // stream
    const int h = (wid - 1) / 3;             // row half: 0 -> rows 0-31, 1 -> 32-63
    float* const dst = out + (size_t)s * BT;
    const int fr = lane >> 4;                // 0..3 : row within quad
    const int fc = (lane & 15) * 4;          // float col 0..60

    for (int st = 0; st < nstage; ++st) {
      if (st > 0) {
        const int tb = (st - 1) * TS;
        const float* const src = &sb[(st - 1) & 1][s][0];
#pragma unroll
        for (int g = 0; g < 8; ++g) {
          const int r = h * 32 + g * 4 + fr;
          f4 v = *reinterpret_cast<const f4*>(&src[r * PITCH + fc]);
          __builtin_nontemporal_store(
              v, reinterpret_cast<f4*>(dst + (size_t)(rowbase + r) * T + tb + fc));
        }
      }
      asm volatile("s_waitcnt lgkmcnt(0)" ::: "memory");
      __builtin_amdgcn_s_barrier();
    }
    // drain final stage (producer is done; no barrier needed)
    {
      const int tb = (nstage - 1) * TS;
      const float* const src = &sb[(nstage - 1) & 1][s][0];
#pragma unroll
      for (int g = 0; g < 8; ++g) {
        const int r = h * 32 + g * 4 + fr;
        f4 v = *reinterpret_cast<const f4*>(&src[r * PITCH + fc]);
        __builtin_nontemporal_store(
            v, reinterpret_cast<f4*>(dst + (size_t)(rowbase + r) * T + tb + fc));
      }
    }
  }
}

// Fallback for shapes not divisible by the tiling (not hit for 16384x2048).
__global__ void ga_fallback(
    const float* __restrict__ precip, const float* __restrict__ K,
    const float* __restrict__ psi, const float* __restrict__ dtheta,
    float* __restrict__ out, int B, int T) {
  int b = blockIdx.x * blockDim.x + threadIdx.x;
  if (b >= B) return;
  const float Kv  = K[b];
  const float kpd = Kv * (psi[b] * dtheta[b]);
  const size_t BT = (size_t)B * (size_t)T;
  float F = 0.0f;
  for (int t = 0; t < T; ++t) {
    float pv   = precip[(size_t)b * T + t];
    float rF   = __builtin_amdgcn_rcpf(fmaxf(F, GA_EPS));
    float fcap = fmaxf(Kv + kpd * rF, GA_MIN_INF);
    float fact = fminf(pv, fcap);
    float ro   = fmaxf(pv - fact, 0.0f);
    F += fact;
    out[(size_t)b * T + t] = fact;
    out[BT + (size_t)b * T + t] = ro;
    out[2 * BT + (size_t)b * T + t] = F;
  }
}

extern "C" void kernel_launch(void* const* d_in, const int* in_sizes, int n_in,
                              void* d_out, int out_size, void* d_ws, size_t ws_size,
                              hipStream_t stream) {
  const float* precip = (const float*)d_in[0];
  const float* K      = (const float*)d_in[1];
  const float* psi    = (const float*)d_in[2];
  const float* dtheta = (const float*)d_in[3];
  float* out = (float*)d_out;

  const int B = in_sizes[1];            // K has B elements
  const int T = in_sizes[0] / B;        // precip is B*T

  if ((B % ROWS) == 0 && (T % TS) == 0 && ((T / 32) % 2) == 0) {
    ga_pc<<<B / ROWS, 448, 0, stream>>>(precip, K, psi, dtheta, out, B, T);
  } else {
    ga_fallback<<<(B + 63) / 64, 64, 0, stream>>>(precip, K, psi, dtheta, out, B, T);
  }
}